// Round 13
// baseline (73.477 us; speedup 1.0000x reference)
//
#include <hip/hip_runtime.h>
#include <math.h>

#define PR 30            // padded rows of h2p
#define PC 32            // padded col stride of h2p; col c <-> px c-1

// 4px x 3kw taps for one co: window = {a.x,a.y,a.z,a.w,b.x,b.y}
__device__ __forceinline__ void tap3(const float4 a, const float2 b,
                                     const float w0, const float w1, const float w2,
                                     float4& acc) {
    acc.x += fabsf(a.x - w0) + fabsf(a.y - w1) + fabsf(a.z - w2);
    acc.y += fabsf(a.y - w0) + fabsf(a.z - w1) + fabsf(a.w - w2);
    acc.z += fabsf(a.z - w0) + fabsf(a.w - w1) + fabsf(b.x - w2);
    acc.w += fabsf(a.w - w0) + fabsf(b.x - w1) + fabsf(b.y - w2);
}

// =========== KA: 1x1 adder(256->64) + PEG depthwise 3x3 + BN1 + ReLU -> h2p ===========
// grid (16 cog, 2 yh, 8 n) = 256 blocks, block 448.
// Block owns 4 h-channels x 14 output rows. h1 lives ONLY in LDS (16 rows incl halo).
__global__ __launch_bounds__(448) void ka_fused(const float* __restrict__ x,
                                                const float* __restrict__ w1,
                                                const float* __restrict__ wpeg,
                                                const float* __restrict__ g1,
                                                const float* __restrict__ b1,
                                                const float* __restrict__ m1,
                                                const float* __restrict__ v1,
                                                float* __restrict__ h2p) {
    __shared__ __align__(16) float smem[3072];   // wsA 1024 + h1t 2048 = 12 KB
    float* wsA = smem;            // [256 ci][4 co]
    float* h1t = smem + 1024;     // [4 co][16 rows][32]  (col = 1+px, borders zero)
    const int tid    = threadIdx.x;
    const int cobase = blockIdx.x * 4;
    const int yh     = blockIdx.y;            // 0..1 (14-row halves)
    const int n      = blockIdx.z;
    const int co     = tid / 112;             // 0..3
    const int rem    = tid % 112;
    const int row    = rem / 7;               // 0..15 (h1 tile row)
    const int q      = rem % 7;               // px-quad

    for (int idx = tid; idx < 1024; idx += 448) {       // stage w1 (coalesced)
        int c2 = idx >> 8, ci = idx & 255;
        wsA[ci * 4 + c2] = w1[(size_t)(cobase + c2) * 256 + ci];
    }
    for (int idx = tid; idx < 512; idx += 448)          // zero h1t (borders stay 0)
        ((float4*)h1t)[idx] = make_float4(0.f, 0.f, 0.f, 0.f);
    __syncthreads();

    // ---- phase A: h1 rows (yh*14-1 .. yh*14+14) for 4 cos ----
    const int gy = yh * 14 - 1 + row;
    if (gy >= 0 && gy < 28) {
        float4 acc = {0.f, 0.f, 0.f, 0.f};
        const float* xp = x + (size_t)n * 256 * 784 + gy * 28 + q * 4;
        #pragma unroll 8
        for (int ci = 0; ci < 256; ++ci) {
            float4 u = *(const float4*)(xp + (size_t)ci * 784);
            float w  = wsA[ci * 4 + co];
            acc.x += fabsf(u.x - w); acc.y += fabsf(u.y - w);
            acc.z += fabsf(u.z - w); acc.w += fabsf(u.w - w);
        }
        float* hd = h1t + co * 512 + row * 32 + 1 + q * 4;
        hd[0] = -acc.x; hd[1] = -acc.y; hd[2] = -acc.z; hd[3] = -acc.w;
    }
    __syncthreads();

    // ---- phase B: depthwise 3x3 + BN1 + ReLU -> h2p interior ----
    if (row < 14) {
        const int c  = cobase + co;
        const int oy = yh * 14 + row;                 // output row 0..27
        const float* wc = wpeg + c * 9;
        const float* hb = h1t + co * 512 + row * 32 + q * 4;  // aligned window start
        float4 acc = {0.f, 0.f, 0.f, 0.f};
        #pragma unroll
        for (int kh = 0; kh < 3; ++kh) {
            float4 a  = *(const float4*)(hb + kh * 32);
            float2 bv = *(const float2*)(hb + kh * 32 + 4);
            tap3(a, bv, wc[kh * 3 + 0], wc[kh * 3 + 1], wc[kh * 3 + 2], acc);
        }
        float inv = g1[c] * rsqrtf(v1[c] + 1e-5f);
        float bb  = b1[c] - m1[c] * inv;
        float* op = h2p + ((size_t)(n * 64 + c) * PR + oy + 1) * PC + 1 + q * 4;
        op[0] = fmaxf(-acc.x * inv + bb, 0.f);
        op[1] = fmaxf(-acc.y * inv + bb, 0.f);
        op[2] = fmaxf(-acc.z * inv + bb, 0.f);
        op[3] = fmaxf(-acc.w * inv + bb, 0.f);
    }
    // ---- h2p halo zeros for this block's 4 planes / row range ----
    for (int idx = tid; idx < 352; idx += 448) {
        if (idx < 224) {                      // rows yh*14+1..+14, cols {0,29,30,31}
            int rr = idx >> 4, k = idx & 15;
            int cc = k >> 2, kk = k & 3;
            int col = kk ? 28 + kk : 0;
            h2p[((size_t)(n * 64 + cobase + cc) * PR + yh * 14 + 1 + rr) * PC + col] = 0.f;
        } else {                              // padded row 0 (yh=0) or 29 (yh=1), all cols
            int j = idx - 224;
            int cc = j >> 5, col = j & 31;
            int prow = yh ? 29 : 0;
            h2p[((size_t)(n * 64 + cobase + cc) * PR + prow) * PC + col] = 0.f;
        }
    }
}

// =========== KB: 3x3 adder(64->64)+BN2+ReLU + 1x1 adder(64->256)+BN3+res+ReLU ===========
// grid (28 Y, 8 n) = 224 blocks, block 448. Block computes ALL 64 h3 channels of one
// output row into LDS, then the 256-channel 1x1 from LDS. ~73 KB LDS, phase-unioned.
__global__ __launch_bounds__(448) void kb_fused(const float* __restrict__ h2p,
                                                const float* __restrict__ w2,
                                                const float* __restrict__ w3,
                                                const float* __restrict__ x,
                                                const float* __restrict__ g2,
                                                const float* __restrict__ b2,
                                                const float* __restrict__ m2,
                                                const float* __restrict__ v2,
                                                const float* __restrict__ g3,
                                                const float* __restrict__ b3,
                                                const float* __restrict__ m3,
                                                const float* __restrict__ v3,
                                                float* __restrict__ out) {
    __shared__ __align__(16) float smem[18688];  // 73 KB
    float*  h3t = smem;                   // [64 ch][32]  (lives phase A-end .. B)
    float*  h2t = smem + 2048;            // [64 ci][3 r][32]          (A only)
    float*  wck = smem + 8192;            // [144 r][68] w2 chunk      (A only)
    float4* pl4 = (float4*)(smem + 2048); // 1792 f4 partials (over dead h2t/wck)
    float*  w3t = smem + 2048;            // [64 ci][260] (B only, over dead A region)
    const int tid    = threadIdx.x;
    const int Y      = blockIdx.x;        // output row
    const int n      = blockIdx.y;
    const int cic    = tid / 112;         // 0..3  ci-split
    const int rem    = tid % 112;
    const int colane = rem / 7;           // 0..15 -> co quad colane*4
    const int q      = rem % 7;           // px-quad

    // stage h2t: h2p rows Y..Y+2, all 64 ci, full 32 cols (halo included)
    for (int idx = tid; idx < 1536; idx += 448) {
        int ci = idx / 24, r2 = idx % 24;
        int r = r2 / 8, c4 = r2 % 8;
        *(float4*)(h2t + ci * 96 + r * 32 + c4 * 4) =
            *(const float4*)(h2p + ((size_t)(n * 64 + ci) * PR + Y + r) * PC + c4 * 4);
    }
    __syncthreads();

    // ---- phase A: 3x3 adder, 4 chunks of 16 ci ----
    float4 acc0 = {0,0,0,0}, acc1 = acc0, acc2 = acc0, acc3 = acc0;
    for (int ch = 0; ch < 4; ++ch) {
        for (int idx = tid; idx < 9216; idx += 448) {    // stage w2 chunk (coalesced)
            int co = idx / 144, r = idx % 144;
            wck[r * 68 + co] = w2[(size_t)co * 576 + ch * 144 + r];
        }
        __syncthreads();
        #pragma unroll
        for (int i = 0; i < 4; ++i) {
            const int cir = cic * 4 + i;          // 0..15 within chunk
            const int ci  = ch * 16 + cir;
            const float* hb = h2t + ci * 96 + q * 4;
            const float* wb = wck + cir * 612 + colane * 4;   // 9 taps * 68
            #pragma unroll
            for (int kh = 0; kh < 3; ++kh) {
                float4 a  = *(const float4*)(hb + kh * 32);
                float2 bv = *(const float2*)(hb + kh * 32 + 4);
                float4 W0 = *(const float4*)(wb + (kh * 3 + 0) * 68);
                float4 W1 = *(const float4*)(wb + (kh * 3 + 1) * 68);
                float4 W2 = *(const float4*)(wb + (kh * 3 + 2) * 68);
                tap3(a, bv, W0.x, W1.x, W2.x, acc0);
                tap3(a, bv, W0.y, W1.y, W2.y, acc1);
                tap3(a, bv, W0.z, W1.z, W2.z, acc2);
                tap3(a, bv, W0.w, W1.w, W2.w, acc3);
            }
        }
        __syncthreads();
    }
    // partials -> pl (over dead h2t/wck), reduce 4-way, BN2+ReLU -> h3t
    pl4[tid * 4 + 0] = acc0;
    pl4[tid * 4 + 1] = acc1;
    pl4[tid * 4 + 2] = acc2;
    pl4[tid * 4 + 3] = acc3;
    __syncthreads();
    if (tid < 112) {                      // colane = tid/7, q = tid%7 (consistent)
        #pragma unroll
        for (int j = 0; j < 4; ++j) {
            float4 s = pl4[tid * 4 + j];
            #pragma unroll
            for (int c = 1; c < 4; ++c) {
                float4 t = pl4[(c * 112 + tid) * 4 + j];
                s.x += t.x; s.y += t.y; s.z += t.z; s.w += t.w;
            }
            const int co = colane * 4 + j;
            float inv = g2[co] * rsqrtf(v2[co] + 1e-5f);
            float bb  = b2[co] - m2[co] * inv;
            float4 o;
            o.x = fmaxf(-s.x * inv + bb, 0.f);
            o.y = fmaxf(-s.y * inv + bb, 0.f);
            o.z = fmaxf(-s.z * inv + bb, 0.f);
            o.w = fmaxf(-s.w * inv + bb, 0.f);
            *(float4*)(h3t + co * 32 + q * 4) = o;
        }
    }
    __syncthreads();

    // stage w3t [ci][260] (coalesced global reads; 8-way LDS write conflict, cheap)
    for (int idx = tid; idx < 16384; idx += 448) {
        int co = idx >> 6, ci = idx & 63;
        w3t[ci * 260 + co] = w3[(size_t)co * 64 + ci];
    }
    __syncthreads();

    // ---- phase B: 1x1 adder 64->256 + BN3 + residual + ReLU ----
    {
        const int bl = tid / 7;           // 0..63 -> co quad bl*4
        const int bq = tid % 7;           // px-quad
        float4 a0 = {0,0,0,0}, a1 = a0, a2 = a0, a3 = a0;
        const float* hb = h3t + bq * 4;
        const float* wb = w3t + bl * 4;
        #pragma unroll 8
        for (int ci = 0; ci < 64; ++ci) {
            float4 h = *(const float4*)(hb + ci * 32);
            float4 w = *(const float4*)(wb + ci * 260);
            a0.x += fabsf(h.x - w.x); a0.y += fabsf(h.y - w.x); a0.z += fabsf(h.z - w.x); a0.w += fabsf(h.w - w.x);
            a1.x += fabsf(h.x - w.y); a1.y += fabsf(h.y - w.y); a1.z += fabsf(h.z - w.y); a1.w += fabsf(h.w - w.y);
            a2.x += fabsf(h.x - w.z); a2.y += fabsf(h.y - w.z); a2.z += fabsf(h.z - w.z); a2.w += fabsf(h.w - w.z);
            a3.x += fabsf(h.x - w.w); a3.y += fabsf(h.y - w.w); a3.z += fabsf(h.z - w.w); a3.w += fabsf(h.w - w.w);
        }
        float4 accs[4] = {a0, a1, a2, a3};
        #pragma unroll
        for (int j = 0; j < 4; ++j) {
            const int co = bl * 4 + j;
            float inv = g3[co] * rsqrtf(v3[co] + 1e-5f);
            float bb  = b3[co] - m3[co] * inv;
            size_t obase = ((size_t)n * 256 + co) * 784 + Y * 28 + bq * 4;
            float4 r = *(const float4*)(x + obase);
            float4 o;
            o.x = fmaxf(-accs[j].x * inv + bb + r.x, 0.f);
            o.y = fmaxf(-accs[j].y * inv + bb + r.y, 0.f);
            o.z = fmaxf(-accs[j].z * inv + bb + r.z, 0.f);
            o.w = fmaxf(-accs[j].w * inv + bb + r.w, 0.f);
            *(float4*)(out + obase) = o;
        }
    }
}

extern "C" void kernel_launch(void* const* d_in, const int* in_sizes, int n_in,
                              void* d_out, int out_size, void* d_ws, size_t ws_size,
                              hipStream_t stream) {
    const float* x  = (const float*)d_in[0];
    const float* w1 = (const float*)d_in[1];
    const float* wp = (const float*)d_in[2];
    const float* w2 = (const float*)d_in[3];
    const float* w3 = (const float*)d_in[4];
    const float* g1 = (const float*)d_in[5];
    const float* b1 = (const float*)d_in[6];
    const float* m1 = (const float*)d_in[7];
    const float* v1 = (const float*)d_in[8];
    const float* g2 = (const float*)d_in[9];
    const float* b2 = (const float*)d_in[10];
    const float* m2 = (const float*)d_in[11];
    const float* v2 = (const float*)d_in[12];
    const float* g3 = (const float*)d_in[13];
    const float* b3 = (const float*)d_in[14];
    const float* m3 = (const float*)d_in[15];
    const float* v3 = (const float*)d_in[16];
    float* out = (float*)d_out;

    float* h2p = (float*)d_ws;   // 512 planes x 30 x 32 = 491520 floats

    ka_fused<<<dim3(16, 2, 8), 448, 0, stream>>>(x, w1, wp, g1, b1, m1, v1, h2p);
    kb_fused<<<dim3(28, 8), 448, 0, stream>>>(h2p, w2, w3, x,
                                              g2, b2, m2, v2, g3, b3, m3, v3, out);
}